// Round 8
// baseline (136.455 us; speedup 1.0000x reference)
//
#include <hip/hip_runtime.h>

// MHA: B=4, T=1024, D=1024, H=16, HD=64. Causal mask, interleaved RoPE.
// bf16 MFMA (16x16x32) everywhere, fp32 accumulate.
// R8: R7's 256x256 8-phase qkv with the race FIXED: K-tile-boundary vmcnt
// moved to end of p3/p7 BEFORE that phase's barrier, so every consuming
// ds_read sits after a collective (vmcnt -> s_barrier) pair. sched_barrier(0)
// pins reads after those barriers. Unconditional hipFuncSetAttribute (no
// static guard). oproj/attn/prep = R6 (passing).

#define T_SEQ 1024
#define NH    16
#define HDIM  64
#define DM    1024
#define MTOK  4096   // B*T

typedef __attribute__((ext_vector_type(8))) short short8;
typedef __attribute__((ext_vector_type(4))) float f32x4;
typedef unsigned short u16;

__device__ __forceinline__ u16 f2bf(float f) {
  unsigned int u = __builtin_bit_cast(unsigned int, f);
  u += 0x7fffu + ((u >> 16) & 1u);
  return (u16)(u >> 16);
}

// async global->LDS, 16B per lane. LDS dest must be wave-uniform base + lane*16.
__device__ __forceinline__ void gll16(const void* g, void* l) {
  __builtin_amdgcn_global_load_lds(
      (const __attribute__((address_space(1))) unsigned int*)(unsigned long long)(g),
      (__attribute__((address_space(3))) unsigned int*)(unsigned int)(unsigned long long)(l),
      16, 0, 0);
}

// ---------------- prep: x->bf16, W->bf16 (fused qkv+o), rope tables ----------------
__global__ void prep_kernel(const float* __restrict__ x,
                            const float* __restrict__ Wq, const float* __restrict__ Wk,
                            const float* __restrict__ Wv, const float* __restrict__ Wo,
                            u16* __restrict__ xb, u16* __restrict__ wall,
                            float* __restrict__ ctab, float* __restrict__ stab) {
  const int bid = blockIdx.x, tid = threadIdx.x;
  if (bid < 8192) {
    const float* src;
    u16* dst;
    int i;
    if (bid < 4096) {
      src = x; dst = xb; i = bid * 256 + tid;
    } else {
      const int w = (bid - 4096) >> 10;
      src = w == 0 ? Wq : w == 1 ? Wk : w == 2 ? Wv : Wo;
      dst = wall + (size_t)w * (DM * DM);
      i = ((bid - 4096) & 1023) * 256 + tid;
    }
    float4 f = ((const float4*)src)[i];
    unsigned long long pk = (unsigned long long)f2bf(f.x)
                          | ((unsigned long long)f2bf(f.y) << 16)
                          | ((unsigned long long)f2bf(f.z) << 32)
                          | ((unsigned long long)f2bf(f.w) << 48);
    ((unsigned long long*)dst)[i] = pk;
  } else {
    const int idx = (bid - 8192) * 256 + tid;  // T*32
    const int t = idx >> 5, i = idx & 31;
    float inv = powf(10000.f, -(float)i * (1.0f / 32.0f));
    float f = (float)t * inv;
    ctab[idx] = cosf(f);
    stab[idx] = sinf(f);
  }
}

// ---------------- qkv: 256x256 8-phase pipelined GEMM + bias + RoPE ----------------
// A=xb [4096][1024], B=wqkv [3072][1024] (row = output col). Grid 192 = 16m x 12n.
// LDS (dynamic 128KB, u16 units): As sections (buf,kh) at (buf*2+kh)*8192,
// Bs = +32768. Section = 128 lds-rows x 8 chunks x 16B; lds-row r holds
// m-rows {2r, 2r+1} of 32 k; physical chunk = ((m&1)*4 + k>>3) ^ (r&7)
// (inverse on global source; same XOR on reads; 2-way max = free).
// Iteration = K-tiles a=2it (sections 0,1), b=2it+1 (sections 2,3).
// Per phase: reads (safe via the LAST vmcnt->barrier pair), one half-stage,
// BAR, 16 MFMA (setprio), BAR. vmcnt(4) at END of p3 (covers tile b) and
// p7 (covers tile c), placed BEFORE that phase's barrier; sched_barrier(0)
// pins the following reads after the barrier. Tail: p3@it7 = vmcnt(0).
__global__ __launch_bounds__(512, 1) void qkv_kernel(
    const u16* __restrict__ xb, const u16* __restrict__ wqkv,
    const float* __restrict__ bq, const float* __restrict__ bk, const float* __restrict__ bv,
    const float* __restrict__ ctab, const float* __restrict__ stab,
    u16* __restrict__ qbuf, u16* __restrict__ kbuf, u16* __restrict__ vt) {
  extern __shared__ __align__(16) u16 smem[];   // 128 KB
  u16* As = smem;
  u16* Bs = smem + 32768;

  const int tid = threadIdx.x, lane = tid & 63, wave = tid >> 6;
  const int wr = wave >> 2, wc = wave & 3;
  const int lin = blockIdx.x;                    // 192 = 8 XCD * 24
  const int swz = (lin & 7) * 24 + (lin >> 3);
  const int m0 = (swz & 15) * 256;
  const int n0 = (swz >> 4) * 256;

  // staging maps (t-invariant)
  int adst[2];
  size_t aofs[2], bofs[2];
#pragma unroll
  for (int l = 0; l < 2; ++l) {
    const int idx = l * 512 + tid, lr = idx >> 3, lc = (idx & 7) ^ (lr & 7);
    const int row = lr * 2 + (lc >> 2), ko = (lc & 3) * 8;
    adst[l] = idx * 8;
    aofs[l] = (size_t)(m0 + row) * DM + ko;
    bofs[l] = (size_t)(n0 + row) * DM + ko;
  }
  auto stgA = [&](int kt, int kh) {
#pragma unroll
    for (int l = 0; l < 2; ++l)
      gll16(&xb[aofs[l] + kt * 64 + kh * 32], &As[((kt & 1) * 2 + kh) * 8192 + adst[l]]);
  };
  auto stgB = [&](int kt, int kh) {
#pragma unroll
    for (int l = 0; l < 2; ++l)
      gll16(&wqkv[bofs[l] + kt * 64 + kh * 32], &Bs[((kt & 1) * 2 + kh) * 8192 + adst[l]]);
  };

  // frag read offsets (u16 units within a section)
  int aoff[2][4], boff[4];
#pragma unroll
  for (int mh = 0; mh < 2; ++mh)
#pragma unroll
    for (int i = 0; i < 4; ++i) {
      const int m = wr * 128 + mh * 64 + i * 16 + (lane & 15), lr = m >> 1;
      const int pc = (((m & 1) << 2) | (lane >> 4)) ^ (lr & 7);
      aoff[mh][i] = lr * 64 + pc * 8;
    }
#pragma unroll
  for (int jn = 0; jn < 4; ++jn) {
    const int n = wc * 64 + jn * 16 + (lane & 15), lr = n >> 1;
    const int pc = (((n & 1) << 2) | (lane >> 4)) ^ (lr & 7);
    boff[jn] = lr * 64 + pc * 8;
  }

  f32x4 acc[8][4];
#pragma unroll
  for (int i = 0; i < 8; ++i)
#pragma unroll
    for (int j = 0; j < 4; ++j)
#pragma unroll
      for (int r = 0; r < 4; ++r) acc[i][j][r] = 0.f;

  short8 af[4], bf[4];
  auto rdA = [&](const u16* base, int mh) {
#pragma unroll
    for (int i = 0; i < 4; ++i) af[i] = *(const short8*)&base[aoff[mh][i]];
  };
  auto rdB = [&](const u16* base) {
#pragma unroll
    for (int jn = 0; jn < 4; ++jn) bf[jn] = *(const short8*)&base[boff[jn]];
  };

#define MM(mb)                                                                       \
  do {                                                                               \
    __builtin_amdgcn_s_setprio(1);                                                   \
    _Pragma("unroll") for (int i = 0; i < 4; ++i)                                    \
      _Pragma("unroll") for (int jn = 0; jn < 4; ++jn)                               \
        acc[(mb) + i][jn] =                                                          \
            __builtin_amdgcn_mfma_f32_16x16x32_bf16(af[i], bf[jn], acc[(mb) + i][jn], 0, 0, 0); \
    __builtin_amdgcn_s_setprio(0);                                                   \
  } while (0)
#define BAR __builtin_amdgcn_s_barrier()
#define SGB __builtin_amdgcn_sched_barrier(0)

  // prologue: 6 half-stages (12 loads/wave), then collective cover of tile 0
  stgA(0, 0); stgB(0, 0); stgA(0, 1); stgB(0, 1); stgA(1, 0); stgB(1, 0);
  asm volatile("s_waitcnt vmcnt(4)" ::: "memory");
  BAR; SGB;

#pragma unroll 1
  for (int it = 0; it < 8; ++it) {
    const int b = 2 * it + 1, c = 2 * it + 2, d = 2 * it + 3;
    const bool full = (it < 7);
    // ---- K-tile a (sections 0,1) ----
    rdB(Bs + 0); rdA(As + 0, 0);         // p0: mh0 kh0
    stgA(b, 1);
    BAR; MM(0); BAR;
    rdA(As + 0, 1);                      // p1: mh1 kh0
    stgB(b, 1);
    BAR; MM(4); BAR;
    rdB(Bs + 8192); rdA(As + 8192, 0);   // p2: mh0 kh1
    if (full) stgA(c, 0);
    BAR; MM(0); BAR;
    rdA(As + 8192, 1);                   // p3: mh1 kh1
    if (full) {
      stgB(c, 0);
      asm volatile("s_waitcnt vmcnt(4)" ::: "memory");   // tile b landed
    } else {
      asm volatile("s_waitcnt vmcnt(0)" ::: "memory");   // tail: tile 15 landed
    }
    BAR; SGB; MM(4); BAR;
    // ---- K-tile b (sections 2,3) ----
    rdB(Bs + 16384); rdA(As + 16384, 0); // p4: mh0 kh0
    if (full) stgA(c, 1);
    BAR; MM(0); BAR;
    rdA(As + 16384, 1);                  // p5: mh1 kh0
    if (full) stgB(c, 1);
    BAR; MM(4); BAR;
    rdB(Bs + 24576); rdA(As + 24576, 0); // p6: mh0 kh1
    if (full) stgA(d, 0);
    BAR; MM(0); BAR;
    rdA(As + 24576, 1);                  // p7: mh1 kh1
    if (full) {
      stgB(d, 0);
      asm volatile("s_waitcnt vmcnt(4)" ::: "memory");   // tile c landed
    }
    BAR; SGB; MM(4); BAR;
  }
#undef MM
#undef BAR
#undef SGB

  // epilogue: bias + RoPE + scatter to q/k/v layouts
  const int mode = n0 >> 10;
  const float* bias = mode == 0 ? bq : (mode == 1 ? bk : bv);
#pragma unroll
  for (int mi = 0; mi < 8; ++mi) {
#pragma unroll
    for (int nj = 0; nj < 4; ++nj) {
      const int e = n0 + wc * 64 + nj * 16 + (lane & 15);
      const float bval = bias[e & 1023];
      const int h = (e >> 6) & 15, hd = e & 63;
#pragma unroll
      for (int r = 0; r < 4; ++r) {
        const int m = m0 + wr * 128 + mi * 16 + ((lane >> 4) * 4) + r;
        const int bb = m >> 10, t = m & 1023;
        float v = acc[mi][nj][r] + bval;
        if (mode < 2) {
          float p = __shfl_xor(v, 1);  // partner within the (even,odd) pair
          const int fi = hd >> 1;
          const float cc = ctab[t * 32 + fi], ss = stab[t * 32 + fi];
          v = (hd & 1) ? (v * cc + p * ss) : (v * cc - p * ss);
          u16* dst = mode == 0 ? qbuf : kbuf;
          dst[(((size_t)(bb * NH + h) * T_SEQ + t) << 6) + hd] = f2bf(v);
        } else {
          vt[(((size_t)(bb * NH + h) * HDIM + hd) << 10) + t] = f2bf(v);
        }
      }
    }
  }
}

// ---------------- double-buffered GEMM mainloop (R6, for oproj) ----------------
template<int BM, int BN, int AL, int BL, int MI, int NJ>
__device__ __forceinline__ void gemm_dbuf(
    const u16* __restrict__ A, const u16* __restrict__ Bw,
    int m0, int n0, u16* As, u16* Bs, f32x4 acc[MI][NJ]) {
  const int tid = threadIdx.x, lane = tid & 63, wave = tid >> 6;
  const int wr = wave >> 1, wc = wave & 1;
  const int NT = DM / 32;

  size_t aofs[AL], bofs[BL];
  int adst[AL], bdst[BL];
#pragma unroll
  for (int l = 0; l < AL; ++l) {
    const int idx = l * 256 + tid, r = idx >> 3, c = (idx & 7) ^ (r & 7);
    aofs[l] = (size_t)(m0 + 2 * r + (c >> 2)) * DM + (c & 3) * 8;
    adst[l] = idx * 8;
  }
#pragma unroll
  for (int l = 0; l < BL; ++l) {
    const int idx = l * 256 + tid, r = idx >> 3, c = (idx & 7) ^ (r & 7);
    bofs[l] = (size_t)(n0 + 2 * r + (c >> 2)) * DM + (c & 3) * 8;
    bdst[l] = idx * 8;
  }

#define STGD(t, b)                                                        \
  do {                                                                    \
    _Pragma("unroll") for (int l = 0; l < AL; ++l)                        \
      gll16(&A[aofs[l] + (t) * 32], &As[(b) * (BM * 32) + adst[l]]);      \
    _Pragma("unroll") for (int l = 0; l < BL; ++l)                        \
      gll16(&Bw[bofs[l] + (t) * 32], &Bs[(b) * (BN * 32) + bdst[l]]);     \
  } while (0)

  const int mrow = lane & 15, q = lane >> 4;
  int aoff[MI], boff[NJ];
#pragma unroll
  for (int i = 0; i < MI; ++i) {
    const int m = wr * (MI * 16) + i * 16 + mrow, r = m >> 1;
    const int p = (((m & 1) << 2) | q) ^ (r & 7);
    aoff[i] = r * 64 + p * 8;
  }
#pragma unroll
  for (int j = 0; j < NJ; ++j) {
    const int n = wc * (NJ * 16) + j * 16 + mrow, r = n >> 1;
    const int p = (((n & 1) << 2) | q) ^ (r & 7);
    boff[j] = r * 64 + p * 8;
  }

  STGD(0, 0);
  __syncthreads();
  for (int t = 0; t < NT; ++t) {
    if (t + 1 < NT) STGD(t + 1, (t + 1) & 1);
    const int boa = (t & 1) * (BM * 32), bob = (t & 1) * (BN * 32);
    short8 af[MI], bf[NJ];
#pragma unroll
    for (int i = 0; i < MI; ++i) af[i] = *(const short8*)&As[boa + aoff[i]];
#pragma unroll
    for (int j = 0; j < NJ; ++j) bf[j] = *(const short8*)&Bs[bob + boff[j]];
#pragma unroll
    for (int i = 0; i < MI; ++i)
#pragma unroll
      for (int j = 0; j < NJ; ++j)
        acc[i][j] = __builtin_amdgcn_mfma_f32_16x16x32_bf16(af[i], bf[j], acc[i][j], 0, 0, 0);
    __syncthreads();
  }
#undef STGD
}

// ---------------- flash attention (unchanged, passing) ----------------
__global__ __launch_bounds__(256) void attn_kernel(
    const u16* __restrict__ qbuf, const u16* __restrict__ kbuf,
    const u16* __restrict__ vtb, u16* __restrict__ ctx) {
  __shared__ __align__(16) u16 Ks[2][64 * 64];   // [kv][hd] swizzled
  __shared__ __align__(16) u16 Vs[2][64 * 64];   // [hd][kv] swizzled (V^T tile)
  __shared__ __align__(16) u16 Psm[4][16 * 64];  // per-wave P, swizzled
  const int bh = blockIdx.x;
  const int b = bh >> 4, h = bh & 15;
  const int tid = threadIdx.x, lane = tid & 63, wave = tid >> 6;
  const u16* Qp = qbuf + (size_t)bh * T_SEQ * HDIM;
  const u16* Kp = kbuf + (size_t)bh * T_SEQ * HDIM;
  const u16* Vp = vtb + (size_t)bh * HDIM * T_SEQ;
  u16* Pw = &Psm[wave][0];

  const int srow = tid >> 3;                     // staging row (0..31, +32 for c=1)
  const int schx = ((tid & 7) ^ (srow & 7)) * 8; // pre-swizzled chunk (u16 offset)
  const int lx = lane & 7;                       // row&7 for all read rows below

#define STG(kvt, bb)                                                            \
  do {                                                                          \
    _Pragma("unroll") for (int c = 0; c < 2; ++c) {                             \
      const int rr = c * 32 + srow;                                             \
      gll16(&Kp[(kvt) * 4096 + rr * 64 + schx], &Ks[bb][c * 2048 + tid * 8]);   \
      gll16(&Vp[(size_t)rr * T_SEQ + (kvt) * 64 + schx], &Vs[bb][c * 2048 + tid * 8]); \
    }                                                                           \
  } while (0)

  for (int phase = 0; phase < 2; ++phase) {
    const int qt = phase ? (15 - (int)blockIdx.y) : (int)blockIdx.y;
    const int q0 = qt * 64;
    const int nkv = qt + 1;
    const int qrow = q0 + wave * 16 + (lane & 15);
    const short8 qf0 = *(const short8*)&Qp[qrow * 64 + ((lane >> 4) * 8)];
    const short8 qf1 = *(const short8*)&Qp[qrow * 64 + 32 + ((lane >> 4) * 8)];

    f32x4 acc_o[4];
    float m_r[4], l_r[4];
#pragma unroll
    for (int i = 0; i < 4; ++i) {
#pragma unroll
      for (int r = 0; r < 4; ++r) acc_o[i][r] = 0.f;
      m_r[i] = -__builtin_inff();
      l_r[i] = 0.f;
    }

    __syncthreads();   // previous phase's readers done before restaging buf0
    STG(0, 0);
    int cur = 0;

    for (int kvt = 0; kvt < nkv; ++kvt) {
      __syncthreads();                       // buf[cur] staged (vmcnt drained)
      if (kvt + 1 < nkv) STG(kvt + 1, cur ^ 1);

      // S = Q K^T (16x64 per wave)
      f32x4 sacc[4];
#pragma unroll
      for (int cb = 0; cb < 4; ++cb) {
#pragma unroll
        for (int r = 0; r < 4; ++r) sacc[cb][r] = 0.f;
        const int krow = cb * 16 + (lane & 15);
        const short8 kf0 = *(const short8*)&Ks[cur][krow * 64 + (((lane >> 4) ^ lx) * 8)];
        const short8 kf1 = *(const short8*)&Ks[cur][krow * 64 + (((4 + (lane >> 4)) ^ lx) * 8)];
        sacc[cb] = __builtin_amdgcn_mfma_f32_16x16x32_bf16(qf0, kf0, sacc[cb], 0, 0, 0);
        sacc[cb] = __builtin_amdgcn_mfma_f32_16x16x32_bf16(qf1, kf1, sacc[cb], 0, 0, 0);
      }
      // scale + causal mask
      const int trow_base = q0 + wave * 16 + ((lane >> 4) * 4);
#pragma unroll
      for (int cb = 0; cb < 4; ++cb) {
        const int scol = kvt * 64 + cb * 16 + (lane & 15);
#pragma unroll
        for (int r = 0; r < 4; ++r) {
          float sv = sacc[cb][r] * 0.125f;
          sacc[cb][r] = (scol > trow_base + r) ? -__builtin_inff() : sv;
        }
      }
      // online softmax (rows live across 16 lanes x 4 col-blocks)
      float mt[4];
#pragma unroll
      for (int r = 0; r < 4; ++r)
        mt[r] = fmaxf(fmaxf(sacc[0][r], sacc[1][r]), fmaxf(sacc[2][r], sacc[3][r]));
#pragma unroll
      for (int off = 1; off < 16; off <<= 1)
#pragma unroll
        for (int r = 0; r < 4; ++r) mt[r] = fmaxf(mt[r], __shfl_xor(mt[r], off));
      float sf[4], lt[4];
#pragma unroll
      for (int r = 0; r < 4; ++r) {
        const float mn = fmaxf(m_r[r], mt[r]);
        sf[r] = __expf(m_r[r] - mn);
        m_r[r] = mn;
        lt[r] = 0.f;
      }
#pragma unroll
      for (int cb = 0; cb < 4; ++cb)
#pragma unroll
        for (int r = 0; r < 4; ++r) {
          const float p = __expf(sacc[cb][r] - m_r[r]);
          sacc[cb][r] = p;
          lt[r] += p;
        }
#pragma unroll
      for (int off = 1; off < 16; off <<= 1)
#pragma unroll
        for (int r = 0; r < 4; ++r) lt[r] += __shfl_xor(lt[r], off);
#pragma unroll
      for (int r = 0; r < 4; ++r) l_r[r] = l_r[r] * sf[r] + lt[r];
#pragma unroll
      for (int hb = 0; hb < 4; ++hb)
#pragma unroll
        for (int r = 0; r < 4; ++r) acc_o[hb][r] *= sf[r];

      // P (C-layout) -> LDS (swizzled) -> A-layout
#pragma unroll
      for (int cb = 0; cb < 4; ++cb)
#pragma unroll
        for (int r = 0; r < 4; ++r) {
          const int prow = (lane >> 4) * 4 + r;
          Pw[prow * 64 + ((cb * 16 + (lane & 15)) ^ ((prow & 7) << 3))] = f2bf(sacc[cb][r]);
        }

      // O += P V
      const int prr = lane & 15;
#pragma unroll
      for (int kc = 0; kc < 2; ++kc) {
        const short8 pf = *(const short8*)&Pw[prr * 64 + (((kc * 4 + (lane >> 4)) ^ lx) * 8)];
#pragma unroll
        for (int hb = 0; hb < 4; ++hb) {
          const int vrow = hb * 16 + (lane & 15);
          const short8 vf = *(const short8*)&Vs[cur][vrow * 64 + (((kc * 4 + (lane >> 4)) ^ lx) * 8)];
          acc_o[hb] = __builtin_amdgcn_mfma_f32_16x16x32_bf16(pf, vf, acc_o[hb], 0, 0, 0);
        }
      }
      cur ^= 1;
    }

    // epilogue: ctx[b][t][h][hd] bf16
#pragma unroll
    for (int hb = 0; hb < 4; ++hb) {
      const int hd = hb * 16 + (lane & 15);
#pragma unroll
      for (int r = 0; r < 4; ++r) {
        const int t = q0 + wave * 16 + ((lane >> 4) * 4) + r;
        const float v = acc_o[hb][r] / l_r[r];
        ctx[((size_t)(b * T_SEQ + t) * NH + h) * HDIM + hd] = f2bf(v);
      }
    }
  }
#undef STG
}

// ---------------- output projection -> fp32 d_out (R6) ----------------
__global__ __launch_bounds__(256, 2) void oproj_kernel(
    const u16* __restrict__ ctx, const u16* __restrict__ Wob,
    const float* __restrict__ bo, float* __restrict__ out) {
  __shared__ __align__(16) u16 As[2 * 64 * 32];    // 8 KB
  __shared__ __align__(16) u16 Bs[2 * 128 * 32];   // 16 KB
  const int lin = blockIdx.x;                      // 512 = 8 * 64
  const int swz = (lin & 7) * 64 + (lin >> 3);
  const int m0 = (swz / 8) * 64;
  const int n0 = (swz % 8) * 128;
  f32x4 acc[2][4];
#pragma unroll
  for (int i = 0; i < 2; ++i)
#pragma unroll
    for (int j = 0; j < 4; ++j)
#pragma unroll
      for (int r = 0; r < 4; ++r) acc[i][j][r] = 0.f;
  gemm_dbuf<64, 128, 1, 2, 2, 4>(ctx, Wob, m0, n0, As, Bs, acc);
  const int lane = threadIdx.x & 63, wave = threadIdx.x >> 6;
  const int wr = wave >> 1, wc = wave & 1;
#pragma unroll
  for (int i = 0; i < 2; ++i)
#pragma unroll
    for (int j = 0; j < 4; ++j) {
      const int e = n0 + wc * 64 + j * 16 + (lane & 15);
      const float bval = bo[e];
#pragma unroll
      for (int r = 0; r < 4; ++r) {
        const int m = m0 + wr * 32 + i * 16 + ((lane >> 4) * 4) + r;
        out[(size_t)m * DM + e] = acc[i][j][r] + bval;
      }
    }
}

extern "C" void kernel_launch(void* const* d_in, const int* in_sizes, int n_in,
                              void* d_out, int out_size, void* d_ws, size_t ws_size,
                              hipStream_t stream) {
  const float* x  = (const float*)d_in[0];
  const float* Wq = (const float*)d_in[1];
  const float* bq = (const float*)d_in[2];
  const float* Wk = (const float*)d_in[3];
  const float* bk = (const float*)d_in[4];
  const float* Wv = (const float*)d_in[5];
  const float* bv = (const float*)d_in[6];
  const float* Wo = (const float*)d_in[7];
  const float* bo = (const float*)d_in[8];

  char* w = (char*)d_ws;
  u16* xb   = (u16*)(w);
  u16* wall = (u16*)(w + (8ull << 20));   // Wq|Wk|Wv|Wo bf16, 2MB each
  u16* wob  = (u16*)(w + (14ull << 20));
  u16* qb   = (u16*)(w + (16ull << 20));
  u16* kb   = (u16*)(w + (24ull << 20));
  u16* vtb  = (u16*)(w + (32ull << 20));
  u16* ctxb = (u16*)(w + (40ull << 20));
  float* ctab = (float*)(w + (48ull << 20));
  float* stab = ctab + T_SEQ * 32;

  hipFuncSetAttribute(reinterpret_cast<const void*>(qkv_kernel),
                      hipFuncAttributeMaxDynamicSharedMemorySize, 131072);

  prep_kernel<<<dim3(8192 + 128), 256, 0, stream>>>(x, Wq, Wk, Wv, Wo, xb, wall, ctab, stab);
  qkv_kernel<<<dim3(192), 512, 131072, stream>>>(
      xb, wall, bq, bk, bv, ctab, stab, qb, kb, vtb);
  attn_kernel<<<dim3(64, 8), 256, 0, stream>>>(qb, kb, vtb, ctxb);
  oproj_kernel<<<dim3(512), 256, 0, stream>>>(ctxb, wob, bo, (float*)d_out);
}

// Round 9
// 110.638 us; speedup vs baseline: 1.2333x; 1.2333x over previous
//
#include <hip/hip_runtime.h>

// MHA: B=4, T=1024, D=1024, H=16, HD=64. Causal mask, interleaved RoPE.
// bf16 MFMA (16x16x32) everywhere, fp32 accumulate.
// R9: qkv = R4-exact 2-phase (proven 48.9us) + L2-aware 1-D n-major grid
// (each XCD's blocks own fixed m-panels -> A/B L2-resident, staging latency
// ~200cy). oproj same mapping. attn: l-sum via MFMA(P, ones) instead of
// 16 shfl_xor per tile; exp2 with folded 0.125*log2e; mask only diagonal.

#define T_SEQ 1024
#define NH    16
#define HDIM  64
#define DM    1024
#define MTOK  4096   // B*T

typedef __attribute__((ext_vector_type(8))) short short8;
typedef __attribute__((ext_vector_type(4))) float f32x4;
typedef unsigned short u16;

__device__ __forceinline__ u16 f2bf(float f) {
  unsigned int u = __builtin_bit_cast(unsigned int, f);
  u += 0x7fffu + ((u >> 16) & 1u);
  return (u16)(u >> 16);
}

// async global->LDS, 16B per lane. LDS dest must be wave-uniform base + lane*16.
__device__ __forceinline__ void gll16(const void* g, void* l) {
  __builtin_amdgcn_global_load_lds(
      (const __attribute__((address_space(1))) unsigned int*)(unsigned long long)(g),
      (__attribute__((address_space(3))) unsigned int*)(unsigned int)(unsigned long long)(l),
      16, 0, 0);
}

// ---------------- prep: x->bf16, W->bf16 (fused qkv+o), rope tables ----------------
__global__ void prep_kernel(const float* __restrict__ x,
                            const float* __restrict__ Wq, const float* __restrict__ Wk,
                            const float* __restrict__ Wv, const float* __restrict__ Wo,
                            u16* __restrict__ xb, u16* __restrict__ wall,
                            float* __restrict__ ctab, float* __restrict__ stab) {
  const int bid = blockIdx.x, tid = threadIdx.x;
  if (bid < 8192) {
    const float* src;
    u16* dst;
    int i;
    if (bid < 4096) {
      src = x; dst = xb; i = bid * 256 + tid;
    } else {
      const int w = (bid - 4096) >> 10;
      src = w == 0 ? Wq : w == 1 ? Wk : w == 2 ? Wv : Wo;
      dst = wall + (size_t)w * (DM * DM);
      i = ((bid - 4096) & 1023) * 256 + tid;
    }
    float4 f = ((const float4*)src)[i];
    unsigned long long pk = (unsigned long long)f2bf(f.x)
                          | ((unsigned long long)f2bf(f.y) << 16)
                          | ((unsigned long long)f2bf(f.z) << 32)
                          | ((unsigned long long)f2bf(f.w) << 48);
    ((unsigned long long*)dst)[i] = pk;
  } else {
    const int idx = (bid - 8192) * 256 + tid;  // T*32
    const int t = idx >> 5, i = idx & 31;
    float inv = powf(10000.f, -(float)i * (1.0f / 32.0f));
    float f = (float)t * inv;
    ctab[idx] = cosf(f);
    stab[idx] = sinf(f);
  }
}

// ---------------- single-barrier pipelined GEMM mainloop (R4, proven) ----------------
// A:[M][1024] bf16, Bw:[N][1024] bf16 (row = output col). BK=64, NT=16.
// 4 waves in 2x2 grid: per-wave output (BM/2) x (BN/2), MI x NJ 16x16 frags.
// LDS layout: row-major [rows][64], 16B chunk c of row r stored at chunk
// position c ^ (r&7) (inverse-swizzle applied to GLOBAL source; reads use
// the same XOR). One __syncthreads per iter.
template<int BM, int BN, int AI, int BI, int MI, int NJ>
__device__ __forceinline__ void gemm_pipe2(
    const u16* __restrict__ A, const u16* __restrict__ Bw,
    int m0, int n0, u16* As, u16* Bs, f32x4 acc[MI][NJ]) {
  const int tid = threadIdx.x, lane = tid & 63, wave = tid >> 6;
  const int wr = wave >> 1, wc = wave & 1;
  const int srcswz = ((lane & 7) ^ (lane >> 3)) * 8;  // u16 offset within K-slice
  const int NT = DM / 64;

#define STAGE2(t, b)                                                         \
  do {                                                                       \
    _Pragma("unroll") for (int i = 0; i < AI; ++i) {                         \
      const int q = (wave * AI + i) * 64 + lane;                             \
      gll16(&A[(size_t)(m0 + (q >> 3)) * DM + (t) * 64 + srcswz],            \
            &As[(b) * BM * 64 + q * 8]);                                     \
    }                                                                        \
    _Pragma("unroll") for (int i = 0; i < BI; ++i) {                         \
      const int q = (wave * BI + i) * 64 + lane;                             \
      gll16(&Bw[(size_t)(n0 + (q >> 3)) * DM + (t) * 64 + srcswz],           \
            &Bs[(b) * BN * 64 + q * 8]);                                     \
    }                                                                        \
  } while (0)

  STAGE2(0, 0);
  __syncthreads();
  int buf = 0;
  const int arow0 = wr * (BM / 2) + (lane & 15);
  const int brow0 = wc * (BN / 2) + (lane & 15);
  const int c0 = (((lane >> 4)) ^ (lane & 7)) * 8;      // kk=0 chunk (XOR row&7 = lane&7)
  const int c1 = ((4 + (lane >> 4)) ^ (lane & 7)) * 8;  // kk=1 chunk
  for (int t = 0; t < NT; ++t) {
    if (t + 1 < NT) STAGE2(t + 1, buf ^ 1);
    short8 af[MI][2], bf[NJ][2];
#pragma unroll
    for (int i = 0; i < MI; ++i) {
      const int r = buf * BM * 64 + (arow0 + i * 16) * 64;
      af[i][0] = *(const short8*)&As[r + c0];
      af[i][1] = *(const short8*)&As[r + c1];
    }
#pragma unroll
    for (int j = 0; j < NJ; ++j) {
      const int r = buf * BN * 64 + (brow0 + j * 16) * 64;
      bf[j][0] = *(const short8*)&Bs[r + c0];
      bf[j][1] = *(const short8*)&Bs[r + c1];
    }
#pragma unroll
    for (int i = 0; i < MI; ++i)
#pragma unroll
      for (int j = 0; j < NJ; ++j) {
        acc[i][j] = __builtin_amdgcn_mfma_f32_16x16x32_bf16(af[i][0], bf[j][0], acc[i][j], 0, 0, 0);
        acc[i][j] = __builtin_amdgcn_mfma_f32_16x16x32_bf16(af[i][1], bf[j][1], acc[i][j], 0, 0, 0);
      }
    __syncthreads();
    buf ^= 1;
  }
#undef STAGE2
}

// ---------------- fused QKV projection + bias + RoPE + layout ----------------
// Tile 128x192, grid 512 1-D, n-major: n0 = lin/32 (32 blocks share B-panel),
// m0 = lin%32 (each XCD's m-tiles fixed mod 8 -> A-panels L2-resident).
__global__ __launch_bounds__(256, 2) void qkv_kernel(
    const u16* __restrict__ xb, const u16* __restrict__ wqkv,
    const float* __restrict__ bq, const float* __restrict__ bk, const float* __restrict__ bv,
    const float* __restrict__ ctab, const float* __restrict__ stab,
    u16* __restrict__ qbuf, u16* __restrict__ kbuf, u16* __restrict__ vt) {
  __shared__ __align__(16) u16 As[2 * 128 * 64];   // 32 KB
  __shared__ __align__(16) u16 Bs[2 * 192 * 64];   // 48 KB
  const int lin = blockIdx.x;                      // 512 = 16 n-groups * 32 m
  const int m0 = (lin & 31) * 128;
  const int n0 = (lin >> 5) * 192;                 // fused col across Wq|Wk|Wv
  f32x4 acc[4][6];
#pragma unroll
  for (int i = 0; i < 4; ++i)
#pragma unroll
    for (int j = 0; j < 6; ++j)
#pragma unroll
      for (int r = 0; r < 4; ++r) acc[i][j][r] = 0.f;
  gemm_pipe2<128, 192, 4, 6, 4, 6>(xb, wqkv, m0, n0, As, Bs, acc);

  const int lane = threadIdx.x & 63, wave = threadIdx.x >> 6;
  const int wr = wave >> 1, wc = wave & 1;
#pragma unroll
  for (int i = 0; i < 4; ++i) {
#pragma unroll
    for (int j = 0; j < 6; ++j) {
      const int e = n0 + wc * 96 + j * 16 + (lane & 15);   // global fused col
      const int mode = e >> 10;                             // 0=q 1=k 2=v (uniform per j-block)
      const float* bias = mode == 0 ? bq : (mode == 1 ? bk : bv);
      const float bval = bias[e & 1023];
      const int h = (e >> 6) & 15, hd = e & 63;
#pragma unroll
      for (int r = 0; r < 4; ++r) {
        const int m = m0 + wr * 64 + i * 16 + ((lane >> 4) * 4) + r;
        const int b = m >> 10, t = m & 1023;
        float v = acc[i][j][r] + bval;
        if (mode < 2) {
          float p = __shfl_xor(v, 1);  // partner within the (even,odd) pair
          const int fi = hd >> 1;
          const float cc = ctab[t * 32 + fi], ss = stab[t * 32 + fi];
          v = (hd & 1) ? (v * cc + p * ss) : (v * cc - p * ss);
          u16* dst = mode == 0 ? qbuf : kbuf;
          dst[(((size_t)(b * NH + h) * T_SEQ + t) << 6) + hd] = f2bf(v);
        } else {
          vt[(((size_t)(b * NH + h) * HDIM + hd) << 10) + t] = f2bf(v);
        }
      }
    }
  }
}

// ---------------- flash attention ----------------
// Block = (b,h) x {q-tile qt, 15-qt}: uniform 17 KV tiles. 4 waves x 16 rows.
// R9: scale folded into exp2 domain (SC = 0.125*log2e); causal mask only on
// the diagonal tile; row-sum l via MFMA(P, ones) accumulator (rescaled like
// acc_o) instead of 16 shfl_xor per tile.
__global__ __launch_bounds__(256) void attn_kernel(
    const u16* __restrict__ qbuf, const u16* __restrict__ kbuf,
    const u16* __restrict__ vtb, u16* __restrict__ ctx) {
  __shared__ __align__(16) u16 Ks[2][64 * 64];   // [kv][hd] swizzled
  __shared__ __align__(16) u16 Vs[2][64 * 64];   // [hd][kv] swizzled (V^T tile)
  __shared__ __align__(16) u16 Psm[4][16 * 64];  // per-wave P, swizzled
  const int bh = blockIdx.x;
  const int b = bh >> 4, h = bh & 15;
  const int tid = threadIdx.x, lane = tid & 63, wave = tid >> 6;
  const u16* Qp = qbuf + (size_t)bh * T_SEQ * HDIM;
  const u16* Kp = kbuf + (size_t)bh * T_SEQ * HDIM;
  const u16* Vp = vtb + (size_t)bh * HDIM * T_SEQ;
  u16* Pw = &Psm[wave][0];
  const float SC = 0.18033688f;                  // 0.125 * log2(e)

  const int srow = tid >> 3;                     // staging row (0..31, +32 for c=1)
  const int schx = ((tid & 7) ^ (srow & 7)) * 8; // pre-swizzled chunk (u16 offset)
  const int lx = lane & 7;                       // row&7 for all read rows below

  short8 onesf;
#pragma unroll
  for (int i = 0; i < 8; ++i) onesf[i] = (short)0x3F80;  // bf16 1.0

#define STG(kvt, bb)                                                            \
  do {                                                                          \
    _Pragma("unroll") for (int c = 0; c < 2; ++c) {                             \
      const int rr = c * 32 + srow;                                             \
      gll16(&Kp[(kvt) * 4096 + rr * 64 + schx], &Ks[bb][c * 2048 + tid * 8]);   \
      gll16(&Vp[(size_t)rr * T_SEQ + (kvt) * 64 + schx], &Vs[bb][c * 2048 + tid * 8]); \
    }                                                                           \
  } while (0)

  for (int phase = 0; phase < 2; ++phase) {
    const int qt = phase ? (15 - (int)blockIdx.y) : (int)blockIdx.y;
    const int q0 = qt * 64;
    const int nkv = qt + 1;
    const int qrow = q0 + wave * 16 + (lane & 15);
    const short8 qf0 = *(const short8*)&Qp[qrow * 64 + ((lane >> 4) * 8)];
    const short8 qf1 = *(const short8*)&Qp[qrow * 64 + 32 + ((lane >> 4) * 8)];

    f32x4 acc_o[4], accl;
    float m_r[4];
#pragma unroll
    for (int i = 0; i < 4; ++i) {
#pragma unroll
      for (int r = 0; r < 4; ++r) acc_o[i][r] = 0.f;
      accl[i] = 0.f;
      m_r[i] = -__builtin_inff();
    }

    __syncthreads();   // previous phase's readers done before restaging buf0
    STG(0, 0);
    int cur = 0;

    for (int kvt = 0; kvt < nkv; ++kvt) {
      __syncthreads();                       // buf[cur] staged (vmcnt drained)
      if (kvt + 1 < nkv) STG(kvt + 1, cur ^ 1);

      // S = Q K^T (16x64 per wave), scaled into exp2 domain
      f32x4 sacc[4];
#pragma unroll
      for (int cb = 0; cb < 4; ++cb) {
#pragma unroll
        for (int r = 0; r < 4; ++r) sacc[cb][r] = 0.f;
        const int krow = cb * 16 + (lane & 15);
        const short8 kf0 = *(const short8*)&Ks[cur][krow * 64 + (((lane >> 4) ^ lx) * 8)];
        const short8 kf1 = *(const short8*)&Ks[cur][krow * 64 + (((4 + (lane >> 4)) ^ lx) * 8)];
        sacc[cb] = __builtin_amdgcn_mfma_f32_16x16x32_bf16(qf0, kf0, sacc[cb], 0, 0, 0);
        sacc[cb] = __builtin_amdgcn_mfma_f32_16x16x32_bf16(qf1, kf1, sacc[cb], 0, 0, 0);
      }
      if (kvt == qt) {
        // diagonal tile: scale + causal mask
        const int trow_base = q0 + wave * 16 + ((lane >> 4) * 4);
#pragma unroll
        for (int cb = 0; cb < 4; ++cb) {
          const int scol = kvt * 64 + cb * 16 + (lane & 15);
#pragma unroll
          for (int r = 0; r < 4; ++r)
            sacc[cb][r] = (scol > trow_base + r) ? -__builtin_inff() : sacc[cb][r] * SC;
        }
      } else {
#pragma unroll
        for (int cb = 0; cb < 4; ++cb)
#pragma unroll
          for (int r = 0; r < 4; ++r) sacc[cb][r] *= SC;
      }
      // online softmax: row-max via 4-round shuffle; row-sum via MFMA below
      float mt[4];
#pragma unroll
      for (int r = 0; r < 4; ++r)
        mt[r] = fmaxf(fmaxf(sacc[0][r], sacc[1][r]), fmaxf(sacc[2][r], sacc[3][r]));
#pragma unroll
      for (int off = 1; off < 16; off <<= 1)
#pragma unroll
        for (int r = 0; r < 4; ++r) mt[r] = fmaxf(mt[r], __shfl_xor(mt[r], off));
      float sf[4];
#pragma unroll
      for (int r = 0; r < 4; ++r) {
        const float mn = fmaxf(m_r[r], mt[r]);
        sf[r] = exp2f(m_r[r] - mn);
        m_r[r] = mn;
      }
#pragma unroll
      for (int cb = 0; cb < 4; ++cb)
#pragma unroll
        for (int r = 0; r < 4; ++r) sacc[cb][r] = exp2f(sacc[cb][r] - m_r[r]);
#pragma unroll
      for (int r = 0; r < 4; ++r) accl[r] *= sf[r];
#pragma unroll
      for (int hb = 0; hb < 4; ++hb)
#pragma unroll
        for (int r = 0; r < 4; ++r) acc_o[hb][r] *= sf[r];

      // P (C-layout) -> LDS (swizzled) -> A-layout
#pragma unroll
      for (int cb = 0; cb < 4; ++cb)
#pragma unroll
        for (int r = 0; r < 4; ++r) {
          const int prow = (lane >> 4) * 4 + r;
          Pw[prow * 64 + ((cb * 16 + (lane & 15)) ^ ((prow & 7) << 3))] = f2bf(sacc[cb][r]);
        }

      // O += P V; l += P * ones
      const int prr = lane & 15;
#pragma unroll
      for (int kc = 0; kc < 2; ++kc) {
        const short8 pf = *(const short8*)&Pw[prr * 64 + (((kc * 4 + (lane >> 4)) ^ lx) * 8)];
        accl = __builtin_amdgcn_mfma_f32_16x16x32_bf16(pf, onesf, accl, 0, 0, 0);
#pragma unroll
        for (int hb = 0; hb < 4; ++hb) {
          const int vrow = hb * 16 + (lane & 15);
          const short8 vf = *(const short8*)&Vs[cur][vrow * 64 + (((kc * 4 + (lane >> 4)) ^ lx) * 8)];
          acc_o[hb] = __builtin_amdgcn_mfma_f32_16x16x32_bf16(pf, vf, acc_o[hb], 0, 0, 0);
        }
      }
      cur ^= 1;
    }

    // epilogue: ctx[b][t][h][hd] bf16
#pragma unroll
    for (int hb = 0; hb < 4; ++hb) {
      const int hd = hb * 16 + (lane & 15);
#pragma unroll
      for (int r = 0; r < 4; ++r) {
        const int t = q0 + wave * 16 + ((lane >> 4) * 4) + r;
        const float v = acc_o[hb][r] / accl[r];
        ctx[((size_t)(b * T_SEQ + t) * NH + h) * HDIM + hd] = f2bf(v);
      }
    }
  }
#undef STG
}

// ---------------- output projection -> fp32 d_out ----------------
// Tile 64x128, grid 512 1-D, n-major: n0 = lin/64, m0 = lin%64.
__global__ __launch_bounds__(256, 2) void oproj_kernel(
    const u16* __restrict__ ctx, const u16* __restrict__ Wob,
    const float* __restrict__ bo, float* __restrict__ out) {
  __shared__ __align__(16) u16 As[2 * 64 * 64];    // 16 KB
  __shared__ __align__(16) u16 Bs[2 * 128 * 64];   // 32 KB
  const int lin = blockIdx.x;                      // 512 = 8 n-groups * 64 m
  const int m0 = (lin & 63) * 64;
  const int n0 = (lin >> 6) * 128;
  f32x4 acc[2][4];
#pragma unroll
  for (int i = 0; i < 2; ++i)
#pragma unroll
    for (int j = 0; j < 4; ++j)
#pragma unroll
      for (int r = 0; r < 4; ++r) acc[i][j][r] = 0.f;
  gemm_pipe2<64, 128, 2, 4, 2, 4>(ctx, Wob, m0, n0, As, Bs, acc);
  const int lane = threadIdx.x & 63, wave = threadIdx.x >> 6;
  const int wr = wave >> 1, wc = wave & 1;
#pragma unroll
  for (int i = 0; i < 2; ++i)
#pragma unroll
    for (int j = 0; j < 4; ++j) {
      const int e = n0 + wc * 64 + j * 16 + (lane & 15);
      const float bval = bo[e];
#pragma unroll
      for (int r = 0; r < 4; ++r) {
        const int m = m0 + wr * 32 + i * 16 + ((lane >> 4) * 4) + r;
        out[(size_t)m * DM + e] = acc[i][j][r] + bval;
      }
    }
}

extern "C" void kernel_launch(void* const* d_in, const int* in_sizes, int n_in,
                              void* d_out, int out_size, void* d_ws, size_t ws_size,
                              hipStream_t stream) {
  const float* x  = (const float*)d_in[0];
  const float* Wq = (const float*)d_in[1];
  const float* bq = (const float*)d_in[2];
  const float* Wk = (const float*)d_in[3];
  const float* bk = (const float*)d_in[4];
  const float* Wv = (const float*)d_in[5];
  const float* bv = (const float*)d_in[6];
  const float* Wo = (const float*)d_in[7];
  const float* bo = (const float*)d_in[8];

  char* w = (char*)d_ws;
  u16* xb   = (u16*)(w);
  u16* wall = (u16*)(w + (8ull << 20));   // Wq|Wk|Wv|Wo bf16, 2MB each
  u16* wob  = (u16*)(w + (14ull << 20));
  u16* qb   = (u16*)(w + (16ull << 20));
  u16* kb   = (u16*)(w + (24ull << 20));
  u16* vtb  = (u16*)(w + (32ull << 20));
  u16* ctxb = (u16*)(w + (40ull << 20));
  float* ctab = (float*)(w + (48ull << 20));
  float* stab = ctab + T_SEQ * 32;

  prep_kernel<<<dim3(8192 + 128), 256, 0, stream>>>(x, Wq, Wk, Wv, Wo, xb, wall, ctab, stab);
  qkv_kernel<<<dim3(512), 256, 0, stream>>>(
      xb, wall, bq, bk, bv, ctab, stab, qb, kb, vtb);
  attn_kernel<<<dim3(64, 8), 256, 0, stream>>>(qb, kb, vtb, ctxb);
  oproj_kernel<<<dim3(512), 256, 0, stream>>>(ctxb, wob, bo, (float*)d_out);
}